// Round 12
// baseline (889.799 us; speedup 1.0000x reference)
//
#include <hip/hip_runtime.h>
#include <hip/hip_fp16.h>
#include <cstdint>
#include <cstddef>

typedef __attribute__((ext_vector_type(8))) short short8;
typedef __attribute__((ext_vector_type(8))) _Float16 h16x8;
typedef __attribute__((ext_vector_type(4))) float f32x4;

// bf16 helpers (RNE)
__device__ __forceinline__ short f2bf(float x) {
  union { float f; unsigned u; } a; a.f = x;
  unsigned r = a.u + 0x7fff + ((a.u >> 16) & 1);
  return (short)(r >> 16);
}
__device__ __forceinline__ float bf2f(short s) {
  union { unsigned u; float f; } a;
  a.u = ((unsigned)(unsigned short)s) << 16; return a.f;
}
// fp16 hi/lo split (v is pre-scaled; residual captured in second fp16)
__device__ __forceinline__ void fsplit16(float v, short& h, short& l) {
  __half a = __float2half(v);
  h = (short)__half_as_ushort(a);
  l = (short)__half_as_ushort(__float2half(v - __half2float(a)));
}

// async global->LDS, 16B per lane; lds dest = wave-uniform base + lane*16
__device__ __forceinline__ void ld16(const void* g, void* l) {
  __builtin_amdgcn_global_load_lds(
      (const __attribute__((address_space(1))) unsigned int*)g,
      (__attribute__((address_space(3))) unsigned int*)l, 16, 0, 0);
}

// ---------------------------------------------------------------------------
// conv1: x[16,3,256,256] -> h1 channel-last fp16 hi/lo [16][128*128][64],
// values scaled x64. k=4 s=2 p=1, ReLU.
// ---------------------------------------------------------------------------
__global__ __launch_bounds__(256) void conv1_kernel(
    const float* __restrict__ x, const float* __restrict__ w,
    const float* __restrict__ bias, short* __restrict__ yh, short* __restrict__ yl)
{
  __shared__ __align__(16) float wl[64 * 48];
  __shared__ float bl[64];
  const int tid = threadIdx.x;
  for (int i = tid; i < 64 * 48; i += 256) wl[i] = w[i];
  if (tid < 64) bl[tid] = bias[tid];
  __syncthreads();
  const int n  = blockIdx.y;
  const int oh = blockIdx.x * 2 + (tid >> 7);
  const int ow = tid & 127;
  const float* xb = x + (size_t)n * 3 * 65536;
  const int ih0 = oh * 2 - 1, iw0 = ow * 2 - 1;
  float xin[48];
#pragma unroll
  for (int ic = 0; ic < 3; ++ic)
#pragma unroll
    for (int kh = 0; kh < 4; ++kh) {
      int ih = ih0 + kh;
      bool rok = (unsigned)ih < 256u;
#pragma unroll
      for (int kw = 0; kw < 4; ++kw) {
        int iw = iw0 + kw;
        xin[ic * 16 + kh * 4 + kw] =
            (rok && (unsigned)iw < 256u) ? xb[ic * 65536 + ih * 256 + iw] : 0.f;
      }
    }
  const size_t ob = ((size_t)n * 16384 + oh * 128 + ow) * 64;
  for (int g = 0; g < 8; ++g) {
    short hs[8], ls[8];
#pragma unroll
    for (int j = 0; j < 8; ++j) {
      const int oc = g * 8 + j;
      float acc = bl[oc];
      const float* wo = &wl[oc * 48];
#pragma unroll
      for (int t = 0; t < 48; ++t) acc = fmaf(wo[t], xin[t], acc);
      acc = fmaxf(acc, 0.f) * 64.f;
      fsplit16(acc, hs[j], ls[j]);
    }
    *(short8*)(yh + ob + g * 8) = *(short8*)hs;
    *(short8*)(yl + ob + g * 8) = *(short8*)ls;
  }
}

// ---------------------------------------------------------------------------
// wpack_conv: encoder conv weights OIHW fp32 -> Wp[oc][K] fp16 hi/lo, x64.
// ---------------------------------------------------------------------------
template <int COUT, int CIN>
__global__ __launch_bounds__(256) void wpack_conv(
    const float* __restrict__ w, short* __restrict__ Wh, short* __restrict__ Wl)
{
  constexpr int K = 16 * CIN;
  const int idx = blockIdx.x * 256 + threadIdx.x;
  const int oc = idx / K, k = idx - oc * K;
  const int kk = k / CIN, ic = k - kk * CIN;
  const int kh = kk >> 2, kw = kk & 3;
  float v = w[(((size_t)oc * CIN + ic) * 4 + kh) * 4 + kw] * 64.f;
  short h, l;
  fsplit16(v, h, l);
  Wh[idx] = h;
  Wl[idx] = l;
}

// ---------------------------------------------------------------------------
// conv_mfma v3: k=4 s=2 p=1 conv as implicit GEMM, fp16 hi/lo x3-MFMA.
// BARRIER-FREE / LDS-FREE: A (weights, 512KB-2MB, L2-resident & shared by
// all blocks) loaded per-lane from global with per-mt base pointers +
// immediate step offsets; B per-lane with OOB->0 (as before). Waves
// free-run; compiler software-pipelines the regular K loop. Numerics
// identical (same operand values, same accumulation order).
// ---------------------------------------------------------------------------
template <int CIN, int HIN, int COUTT, bool RELU, bool OUTF>
__global__ __launch_bounds__(256) void conv_mfma(
    const short* __restrict__ inh, const short* __restrict__ inl,
    const short* __restrict__ Wph, const short* __restrict__ Wpl,
    const float* __restrict__ bias,
    short* __restrict__ outh, short* __restrict__ outl,
    float* __restrict__ outf)
{
  constexpr int K = 16 * CIN;
  constexpr int HOUT = HIN / 2;
  constexpr int MT = 128, NPX = 128;
  constexpr int GS = (HOUT == 64) ? 6 : 5;
  constexpr int NS = K / 32;
  constexpr float RS = 1.f / 4096.f;
  const int tid = threadIdx.x;
  const int w = tid >> 6, lane = tid & 63;
  const int wm = w >> 1, wn = w & 1;
  const int kgl = lane >> 4, cl = lane & 15;
  const int n = blockIdx.z;
  const int oc0 = blockIdx.y * MT;
  const int oh0 = blockIdx.x * (NPX / HOUT);

  f32x4 acc[4][4];
#pragma unroll
  for (int i = 0; i < 4; ++i)
#pragma unroll
    for (int j = 0; j < 4; ++j) acc[i][j] = (f32x4){0.f, 0.f, 0.f, 0.f};

  // per-lane A fragment base pointers (static mt indexing)
  const short* pWh[4];
  const short* pWl[4];
#pragma unroll
  for (int mt = 0; mt < 4; ++mt) {
    size_t ro = (size_t)(oc0 + wm * 64 + mt * 16 + cl) * K + kgl * 8;
    pWh[mt] = Wph + ro;
    pWl[mt] = Wpl + ro;
  }
  // per-lane B pixel coords (fixed across steps)
  const h16x8 zzh = {0, 0, 0, 0, 0, 0, 0, 0};
  int bm[4];
#pragma unroll
  for (int nt = 0; nt < 4; ++nt) bm[nt] = wn * 64 + nt * 16 + cl;

#pragma unroll 2
  for (int s = 0; s < NS; ++s) {
    const int kc = s * 32;
    const int kk = kc / CIN, ic0 = kc % CIN;
    const int kh = kk >> 2, kw = kk & 3;
    h16x8 ah[4], al[4], bh[4], blv[4];
#pragma unroll
    for (int mt = 0; mt < 4; ++mt) {
      ah[mt] = *(const h16x8*)(pWh[mt] + kc);
      al[mt] = *(const h16x8*)(pWl[mt] + kc);
    }
#pragma unroll
    for (int nt = 0; nt < 4; ++nt) {
      int m = bm[nt];
      int ih = 2 * (oh0 + (m >> GS)) - 1 + kh;
      int iw = 2 * (m & (HOUT - 1)) - 1 + kw;
      bool ok = ((unsigned)ih < (unsigned)HIN) && ((unsigned)iw < (unsigned)HIN);
      size_t go = ok ? ((size_t)((n * HIN + ih) * HIN + iw) * CIN + ic0 + kgl * 8)
                     : (size_t)(ic0 + kgl * 8);
      h16x8 vh = *(const h16x8*)(inh + go);
      h16x8 vl = *(const h16x8*)(inl + go);
      bh[nt] = ok ? vh : zzh;
      blv[nt] = ok ? vl : zzh;
    }
#pragma unroll
    for (int mt = 0; mt < 4; ++mt)
#pragma unroll
      for (int nt = 0; nt < 4; ++nt) {
        acc[mt][nt] = __builtin_amdgcn_mfma_f32_16x16x32_f16(
            ah[mt], bh[nt], acc[mt][nt], 0, 0, 0);
        acc[mt][nt] = __builtin_amdgcn_mfma_f32_16x16x32_f16(
            ah[mt], blv[nt], acc[mt][nt], 0, 0, 0);
        acc[mt][nt] = __builtin_amdgcn_mfma_f32_16x16x32_f16(
            al[mt], bh[nt], acc[mt][nt], 0, 0, 0);
      }
  }
  // C/D: oc = wm*64+mt*16+kgl*4+reg, px = wn*64+nt*16+cl
#pragma unroll
  for (int mt = 0; mt < 4; ++mt) {
    const int oc = wm * 64 + mt * 16 + kgl * 4;
    const float4 bv = *(const float4*)&bias[oc0 + oc];
#pragma unroll
    for (int nt = 0; nt < 4; ++nt) {
      const int px = wn * 64 + nt * 16 + cl;
      const int oh = oh0 + (px >> GS), ow = px & (HOUT - 1);
      const size_t ob =
          ((size_t)n * (HOUT * HOUT) + oh * HOUT + ow) * COUTT + oc0 + oc;
      float v0 = acc[mt][nt][0] * RS + bv.x;
      float v1 = acc[mt][nt][1] * RS + bv.y;
      float v2 = acc[mt][nt][2] * RS + bv.z;
      float v3 = acc[mt][nt][3] * RS + bv.w;
      if (RELU) {
        v0 = fmaxf(v0, 0.f); v1 = fmaxf(v1, 0.f);
        v2 = fmaxf(v2, 0.f); v3 = fmaxf(v3, 0.f);
      }
      if constexpr (OUTF) {
        ushort4 s;
        s.x = __half_as_ushort(__float2half(v0));
        s.y = __half_as_ushort(__float2half(v1));
        s.z = __half_as_ushort(__float2half(v2));
        s.w = __half_as_ushort(__float2half(v3));
        *(ushort4*)((unsigned short*)outh + ob) = s;
        *(float4*)(outf + ob) = make_float4(v0, v1, v2, v3);
      } else {
        short4 hh, ll;
        fsplit16(v0 * 64.f, hh.x, ll.x);
        fsplit16(v1 * 64.f, hh.y, ll.y);
        fsplit16(v2 * 64.f, hh.z, ll.z);
        fsplit16(v3 * 64.f, hh.w, ll.w);
        *(short4*)(outh + ob) = hh;
        *(short4*)(outl + ob) = ll;
      }
    }
  }
}

// ---------------------------------------------------------------------------
// cb_convert: codebook fp32 -> bf16 hi/lo (decoder gather) + fp16 (vq scoring)
// ---------------------------------------------------------------------------
__global__ __launch_bounds__(256) void cb_convert(
    const float* __restrict__ cb, short* __restrict__ cbh,
    short* __restrict__ cbl, short* __restrict__ cb16)
{
  const int g = blockIdx.x * 256 + threadIdx.x;
  const float* p = cb + (size_t)g * 8;
  short hs[8], ls[8], fs[8];
#pragma unroll
  for (int u = 0; u < 8; ++u) {
    float v = p[u];
    short h = f2bf(v);
    hs[u] = h;
    ls[u] = f2bf(v - bf2f(h));
    fs[u] = (short)__half_as_ushort(__float2half(v));
  }
  *(short8*)(cbh + (size_t)g * 8) = *(short8*)hs;
  *(short8*)(cbl + (size_t)g * 8) = *(short8*)ls;
  *(short8*)(cb16 + (size_t)g * 8) = *(short8*)fs;
}

// ---------------------------------------------------------------------------
// vq_mfma v10 (unchanged from the verified 828us run)
// ---------------------------------------------------------------------------
__global__ __launch_bounds__(256, 2) void vq_mfma(
    const short* __restrict__ cb16, const short* __restrict__ ft16,
    float4* __restrict__ t4v)
{
  __shared__ __align__(16) short Ah[3][4 * 128 * 8];  // 3 x 8 KB
  __shared__ __align__(16) float MrgV[256 * 4];       // 4 KB merge scratch
  const int tid = threadIdx.x;
  const int w = tid >> 6, lane = tid & 63;
  const int wm = w >> 1, wn = w & 1;
  const int tok0 = blockIdx.x * 128;
  const int split = blockIdx.y;  // 0..7, 1024 codes each
  const int kgl = lane >> 4, cl = lane & 15;
  const int i0 = w * 128;

  // B fragments: loaded once, live whole kernel (128 VGPR, all-static idx)
  h16x8 breg[8][4];
#pragma unroll
  for (int s = 0; s < 8; ++s)
#pragma unroll
    for (int nt = 0; nt < 4; ++nt)
      breg[s][nt] = *(const h16x8*)(ft16 +
          ((size_t)(tok0 + wn * 64 + nt * 16 + cl)) * 256 + s * 32 + kgl * 8);

  // stage A chunk g (tile = g>>3, s = g&7) into buffer b: 2 ld16 per thread
  auto stageA = [&](int g, int b) {
    const int tile = g >> 3, s = g & 7;
    const int code0 = split * 1024 + tile * 128;
    const int kc = s * 32;
#pragma unroll
    for (int rep = 0; rep < 2; ++rep) {
      int ib = i0 + rep * 64;
      int i = ib + lane;
      int m = i & 127, kg = i >> 7;
      size_t go = (size_t)(code0 + m) * 256 + kc + kg * 8;
      ld16(cb16 + go, &Ah[b][ib * 8]);
    }
  };

  f32x4 acc[4][4];

  // running top-2 per token column (index packed in low 11 mantissa bits)
  float m1[4], m2[4];
#pragma unroll
  for (int nt = 0; nt < 4; ++nt) { m1[nt] = -3.4e38f; m2[nt] = -3.4e38f; }
  const unsigned orbase0 = (unsigned)(wm * 64 + kgl * 4);
  auto fold = [&](int tile) {
    const unsigned orb = (unsigned)(tile * 128) + orbase0;
#pragma unroll
    for (int nt = 0; nt < 4; ++nt)
#pragma unroll
      for (int mt = 0; mt < 4; ++mt)
#pragma unroll
        for (int r = 0; r < 4; ++r) {
          union { float f; unsigned u; } pv;
          pv.f = acc[mt][nt][r];
          pv.u = (pv.u & 0xFFFFF800u) | (orb + (unsigned)(mt * 16 + r));
          float t = fminf(m1[nt], pv.f);
          m1[nt] = fmaxf(m1[nt], pv.f);
          m2[nt] = fmaxf(m2[nt], t);
        }
  };

  // one chunk's compute: STATIC s (breg index), runtime LDS buffer b
  auto computeS = [&](int b, int s_static, bool first) {
    h16x8 ah[4];
#pragma unroll
    for (int mt = 0; mt < 4; ++mt) {
      int row = wm * 64 + mt * 16 + cl;
      ah[mt] = *(const h16x8*)&Ah[b][(kgl * 128 + row) * 8];
    }
    if (first) {
      f32x4 z4 = (f32x4){0.f, 0.f, 0.f, 0.f};
#pragma unroll
      for (int mt = 0; mt < 4; ++mt)
#pragma unroll
        for (int nt = 0; nt < 4; ++nt)
          acc[mt][nt] = __builtin_amdgcn_mfma_f32_16x16x32_f16(
              ah[mt], breg[s_static][nt], z4, 0, 0, 0);
    } else {
#pragma unroll
      for (int mt = 0; mt < 4; ++mt)
#pragma unroll
        for (int nt = 0; nt < 4; ++nt)
          acc[mt][nt] = __builtin_amdgcn_mfma_f32_16x16x32_f16(
              ah[mt], breg[s_static][nt], acc[mt][nt], 0, 0, 0);
    }
  };

  // pipeline: depth-2 prefetch, counted vmcnt, raw barriers.
  stageA(0, 0);
  stageA(1, 1);
  asm volatile("s_waitcnt vmcnt(0)" ::: "memory");
  __builtin_amdgcn_sched_barrier(0);
  __builtin_amdgcn_s_barrier();
  for (int tile = 0; tile < 7; ++tile) {
#pragma unroll
    for (int s = 0; s < 8; ++s) {   // s is compile-time under full unroll
      const int g = tile * 8 + s;
      asm volatile("s_waitcnt vmcnt(2)" ::: "memory");
      __builtin_amdgcn_sched_barrier(0);
      __builtin_amdgcn_s_barrier();
      computeS(g % 3, s, s == 0);
      stageA(g + 2, (g + 2) % 3);   // max g+2 = 57 < 64
    }
    fold(tile);
  }
#pragma unroll
  for (int s = 0; s < 8; ++s) {     // tile 7: g = 56..63
    const int g = 56 + s;
    if (s < 7) {
      asm volatile("s_waitcnt vmcnt(2)" ::: "memory");
    } else {
      asm volatile("s_waitcnt vmcnt(0)" ::: "memory");
    }
    __builtin_amdgcn_sched_barrier(0);
    __builtin_amdgcn_s_barrier();
    computeS(g % 3, s, s == 0);
    if (g + 2 < 64) stageA(g + 2, (g + 2) % 3);
  }
  fold(7);

  // merge: butterfly over kgl (lanes ^16, ^32), then cross-wm via LDS
#pragma unroll
  for (int nt = 0; nt < 4; ++nt) {
    float mv[4] = {m1[nt], m2[nt], -3.4e38f, -3.4e38f};
#pragma unroll
    for (int st = 16; st < 64; st <<= 1) {
      float ov[4];
#pragma unroll
      for (int k = 0; k < 4; ++k) ov[k] = __shfl_xor(mv[k], st);
#pragma unroll
      for (int k = 0; k < 4; ++k) {
        if (ov[k] > mv[3]) {
          mv[3] = ov[k];
#pragma unroll
          for (int q = 3; q > 0; --q)
            if (mv[q] > mv[q - 1]) {
              float tv = mv[q]; mv[q] = mv[q - 1]; mv[q - 1] = tv;
            }
        }
      }
    }
    if (lane < 16) {
      int tl = wn * 64 + nt * 16 + cl;
#pragma unroll
      for (int k = 0; k < 4; ++k) MrgV[(wm * 128 + tl) * 4 + k] = mv[k];
    }
  }
  __syncthreads();
  if (tid < 128) {
    int tl = tid;
    float mv[4];
#pragma unroll
    for (int k = 0; k < 4; ++k) mv[k] = MrgV[tl * 4 + k];
#pragma unroll
    for (int k = 0; k < 4; ++k) {
      float ov = MrgV[(128 + tl) * 4 + k];
      if (ov > mv[3]) {
        mv[3] = ov;
#pragma unroll
        for (int q = 3; q > 0; --q)
          if (mv[q] > mv[q - 1]) {
            float tv = mv[q]; mv[q] = mv[q - 1]; mv[q - 1] = tv;
          }
      }
    }
    size_t o = (size_t)split * 16384 + tok0 + tl;
    t4v[o] = make_float4(mv[0], mv[1], mv[2], mv[3]);
  }
}

// ---------------------------------------------------------------------------
// vq_rescore: 8 splits x top-4 packed candidates (id in low mantissa bits) ->
// keep top-4 by packed fp16-score, exact fp32 rescore vs featc, argmax
// (idx-asc tie-break).
// ---------------------------------------------------------------------------
__global__ __launch_bounds__(256) void vq_rescore(
    const float4* __restrict__ t4v, const float* __restrict__ featc,
    const float* __restrict__ cb, int* __restrict__ fidx,
    float* __restrict__ idx_out)
{
  const int t = blockIdx.x * 256 + threadIdx.x;
  float vs[4] = {-3.4e38f, -3.4e38f, -3.4e38f, -3.4e38f};
  int is[4] = {0, 0, 0, 0};
#pragma unroll
  for (int sp = 0; sp < 8; ++sp) {
    float4 v4 = t4v[(size_t)sp * 16384 + t];
    float vv[4] = {v4.x, v4.y, v4.z, v4.w};
#pragma unroll
    for (int k = 0; k < 4; ++k) {
      float v = vv[k];
      union { float f; unsigned u; } pu; pu.f = v;
      int ii = sp * 1024 + (int)(pu.u & 0x7FFu);
      if (v > vs[3]) {
        vs[3] = v; is[3] = ii;
#pragma unroll
        for (int q = 3; q > 0; --q)
          if (vs[q] > vs[q - 1]) {
            float tv = vs[q]; vs[q] = vs[q - 1]; vs[q - 1] = tv;
            int ti = is[q]; is[q] = is[q - 1]; is[q - 1] = ti;
          }
      }
    }
  }
  const float4* fc = (const float4*)(featc + (size_t)t * 256);
  const float4* c0 = (const float4*)(cb + (size_t)is[0] * 256);
  const float4* c1 = (const float4*)(cb + (size_t)is[1] * 256);
  const float4* c2 = (const float4*)(cb + (size_t)is[2] * 256);
  const float4* c3 = (const float4*)(cb + (size_t)is[3] * 256);
  float s0 = 0.f, s1 = 0.f, s2 = 0.f, s3 = 0.f;
  for (int k4 = 0; k4 < 64; ++k4) {
    float4 f = fc[k4];
    float4 w0 = c0[k4], w1 = c1[k4], w2 = c2[k4], w3 = c3[k4];
    s0 = fmaf(w0.x, f.x, fmaf(w0.y, f.y, fmaf(w0.z, f.z, fmaf(w0.w, f.w, s0))));
    s1 = fmaf(w1.x, f.x, fmaf(w1.y, f.y, fmaf(w1.z, f.z, fmaf(w1.w, f.w, s1))));
    s2 = fmaf(w2.x, f.x, fmaf(w2.y, f.y, fmaf(w2.z, f.z, fmaf(w2.w, f.w, s2))));
    s3 = fmaf(w3.x, f.x, fmaf(w3.y, f.y, fmaf(w3.z, f.z, fmaf(w3.w, f.w, s3))));
  }
  float best = s0; int bi = is[0];
  float sv[3] = {s1, s2, s3};
  int si2[3] = {is[1], is[2], is[3]};
#pragma unroll
  for (int c = 0; c < 3; ++c)
    if (sv[c] > best || (sv[c] == best && si2[c] < bi)) { best = sv[c]; bi = si2[c]; }
  fidx[t] = bi;
  idx_out[t] = (float)bi;
}

// ---------------------------------------------------------------------------
// wpack: deconv weights -> Apack[par][oc][K], K=(kk*CIN+ic), bf16 hi/lo.
// ---------------------------------------------------------------------------
template <int COUT, int CIN>
__global__ __launch_bounds__(256) void wpack(
    const float* __restrict__ w, short* __restrict__ Ah, short* __restrict__ Al)
{
  constexpr int K = 4 * CIN;
  const int idx = blockIdx.x * 256 + threadIdx.x;
  const int par = idx / (COUT * K);
  const int rem = idx % (COUT * K);
  const int oc = rem / K;
  const int k = rem % K;
  const int kk = k / CIN, ic = k % CIN;
  const int kh = 2 * (kk >> 1) + (par >> 1);
  const int kw = 2 * (kk & 1) + (par & 1);
  float v = w[(((size_t)oc * CIN + ic) * 4 + kh) * 4 + kw];
  short h = f2bf(v);
  Ah[idx] = h;
  Al[idx] = f2bf(v - bf2f(h));
}

// ---------------------------------------------------------------------------
// gather2: qT[token][ch] bf16 hi/lo = rows of cbh/cbl (pure row copy).
// ---------------------------------------------------------------------------
__global__ __launch_bounds__(256) void gather2(
    const short* __restrict__ cbh, const short* __restrict__ cbl,
    const int* __restrict__ fidx, short* __restrict__ qTh, short* __restrict__ qTl)
{
  const int tid = threadIdx.x;
  const int gt = blockIdx.x * 64 + (tid >> 2);
  const int part = tid & 3;
  const int code = fidx[gt];
  const short8* sh = (const short8*)(cbh + (size_t)code * 256 + part * 64);
  const short8* sl = (const short8*)(cbl + (size_t)code * 256 + part * 64);
  short8* dh = (short8*)(qTh + (size_t)gt * 256 + part * 64);
  short8* dl = (short8*)(qTl + (size_t)gt * 256 + part * 64);
#pragma unroll
  for (int j = 0; j < 8; ++j) { dh[j] = sh[j]; dl[j] = sl[j]; }
}

// ---------------------------------------------------------------------------
// deconv_mfma v3: ConvTranspose2d(k4,s2,p1)+ReLU as per-parity GEMM, bf16x3
// MFMA. BARRIER-FREE / LDS-FREE: A-pack per-lane from global (L2-resident,
// shared by all blocks of the parity); B per-lane with OOB->0. Numerics
// identical to the verified version.
// ---------------------------------------------------------------------------
template <int CIN, int GRID, int COUT, int NPX, int WM, int WN, bool OUT_HALF>
__global__ __launch_bounds__(256) void deconv_mfma(
    const short* __restrict__ inh, const short* __restrict__ inl,
    const short* __restrict__ Aph, const short* __restrict__ Apl,
    const float* __restrict__ bias, void* __restrict__ out_h,
    void* __restrict__ out_l)
{
  constexpr int K = 4 * CIN, HOUT = 2 * GRID;
  constexpr int GS = (GRID == 32) ? 5 : 6;
  constexpr int NS = K / 32;
  const int tid = threadIdx.x;
  const int w = tid >> 6, lane = tid & 63;
  const int wm = w / WN, wn = w % WN;
  const int kgl = lane >> 4, cl = lane & 15;
  const int par = blockIdx.y, n = blockIdx.z;
  const int pr = par >> 1, pc = par & 1;
  const int Ut0 = blockIdx.x * (NPX / GRID);

  f32x4 acc[4][4];
#pragma unroll
  for (int i = 0; i < 4; ++i)
#pragma unroll
    for (int j = 0; j < 4; ++j) acc[i][j] = (f32x4){0.f, 0.f, 0.f, 0.f};

  // per-lane A fragment base pointers (static mt indexing)
  const short* pAh[4];
  const short* pAl[4];
#pragma unroll
  for (int mt = 0; mt < 4; ++mt) {
    size_t ro = ((size_t)(par * COUT + wm * 64 + mt * 16 + cl)) * K + kgl * 8;
    pAh[mt] = Aph + ro;
    pAl[mt] = Apl + ro;
  }
  const short8 zz = {0, 0, 0, 0, 0, 0, 0, 0};
  int bm[4];
#pragma unroll
  for (int nt = 0; nt < 4; ++nt) bm[nt] = wn * 64 + nt * 16 + cl;

#pragma unroll 2
  for (int s = 0; s < NS; ++s) {
    const int kc = s * 32;
    const int kk = kc / CIN, ic0 = kc % CIN;
    const int dr = (kk >> 1) + pr - 1, dc = (kk & 1) + pc - 1;
    short8 ah[4], al[4], bh[4], blo[4];
#pragma unroll
    for (int mt = 0; mt < 4; ++mt) {
      ah[mt] = *(const short8*)(pAh[mt] + kc);
      al[mt] = *(const short8*)(pAl[mt] + kc);
    }
#pragma unroll
    for (int nt = 0; nt < 4; ++nt) {
      int m = bm[nt];
      int sU = Ut0 + (m >> GS) + dr;
      int sV = (m & (GRID - 1)) + dc;
      bool ok = (unsigned)sU < (unsigned)GRID && (unsigned)sV < (unsigned)GRID;
      long pix = (long)(n * GRID + sU) * GRID + sV;
      size_t go = ok ? (size_t)(pix * CIN + ic0 + kgl * 8)
                     : (size_t)(ic0 + kgl * 8);
      short8 vh = *(const short8*)(inh + go);
      short8 vl = *(const short8*)(inl + go);
      bh[nt] = ok ? vh : zz;
      blo[nt] = ok ? vl : zz;
    }
#pragma unroll
    for (int mt = 0; mt < 4; ++mt)
#pragma unroll
      for (int nt = 0; nt < 4; ++nt) {
        acc[mt][nt] = __builtin_amdgcn_mfma_f32_16x16x32_bf16(
            ah[mt], bh[nt], acc[mt][nt], 0, 0, 0);
        acc[mt][nt] = __builtin_amdgcn_mfma_f32_16x16x32_bf16(
            ah[mt], blo[nt], acc[mt][nt], 0, 0, 0);
        acc[mt][nt] = __builtin_amdgcn_mfma_f32_16x16x32_bf16(
            al[mt], bh[nt], acc[mt][nt], 0, 0, 0);
      }
  }
#pragma unroll
  for (int mt = 0; mt < 4; ++mt) {
    const int oc = wm * 64 + mt * 16 + kgl * 4;
    const float4 bv = *(const float4*)&bias[oc];
#pragma unroll
    for (int nt = 0; nt < 4; ++nt) {
      const int px = wn * 64 + nt * 16 + cl;
      const int U = Ut0 + (px >> GS), V = px & (GRID - 1);
      const int r = 2 * U + pr, c = 2 * V + pc;
      const size_t ob = ((size_t)n * HOUT * HOUT + (size_t)r * HOUT + c) * COUT + oc;
      float v0 = fmaxf(acc[mt][nt][0] + bv.x, 0.f);
      float v1 = fmaxf(acc[mt][nt][1] + bv.y, 0.f);
      float v2 = fmaxf(acc[mt][nt][2] + bv.z, 0.f);
      float v3 = fmaxf(acc[mt][nt][3] + bv.w, 0.f);
      if constexpr (OUT_HALF) {
        ushort4 s;
        s.x = __half_as_ushort(__float2half(v0));
        s.y = __half_as_ushort(__float2half(v1));
        s.z = __half_as_ushort(__float2half(v2));
        s.w = __half_as_ushort(__float2half(v3));
        *(ushort4*)((unsigned short*)out_h + ob) = s;
      } else {
        short4 hh, ll;
        hh.x = f2bf(v0); ll.x = f2bf(v0 - bf2f(hh.x));
        hh.y = f2bf(v1); ll.y = f2bf(v1 - bf2f(hh.y));
        hh.z = f2bf(v2); ll.z = f2bf(v2 - bf2f(hh.z));
        hh.w = f2bf(v3); ll.w = f2bf(v3 - bf2f(hh.w));
        *(short4*)((short*)out_h + ob) = hh;
        *(short4*)((short*)out_l + ob) = ll;
      }
    }
  }
}

// ---------------------------------------------------------------------------
// deconv3: d2T[n][pix(128x128)][64] fp16 -> recon[16,3,256,256] (no ReLU).
// ---------------------------------------------------------------------------
__global__ __launch_bounds__(256) void deconv3_kernel(
    const __half* __restrict__ d2, const float* __restrict__ w,
    const float* __restrict__ bias, float* __restrict__ y)
{
  __shared__ __align__(16) float Xl[108 * 68];
  __shared__ __align__(16) float wl[4 * 4 * 3 * 64];
  const int tid = threadIdx.x;
  for (int i = tid; i < 3072; i += 256) {
    int oc = i >> 10, ic = (i >> 4) & 63, kh = (i >> 2) & 3, kw = i & 3;
    int par = (kh & 1) * 2 + (kw & 1), kidx = (kh >> 1) * 2 + (kw >> 1);
    wl[((par * 4 + kidx) * 3 + oc) * 64 + ic] = w[i];
  }
  const int n = blockIdx.z, r0 = blockIdx.y * 8, c0 = blockIdx.x * 32;
  const int gr0 = (r0 >> 1) - 1, gc0 = (c0 >> 1) - 1;
  for (int e = tid; e < 1728; e += 256) {
    int pl = e >> 4, sub = e & 15;
    int rr = pl / 18, cc = pl - rr * 18;
    int gr = gr0 + rr, gc = gc0 + cc;
    float4 v = make_float4(0.f, 0.f, 0.f, 0.f);
    if ((unsigned)gr < 128u && (unsigned)gc < 128u) {
      const __half2* p =
          (const __half2*)(d2 + ((size_t)(n * 16384 + gr * 128 + gc) * 64 + sub * 4));
      float2 f0 = __half22float2(p[0]);
      float2 f1 = __half22float2(p[1]);
      v = make_float4(f0.x, f0.y, f1.x, f1.y);
    }
    *(float4*)&Xl[pl * 68 + sub * 4] = v;
  }
  __syncthreads();
  const int wv = tid >> 6, lane = tid & 63;
  const int pr = wv >> 1, pc = wv & 1;
  const int Ul = lane >> 4, Vl = lane & 15;
  float a0 = bias[0], a1 = bias[1], a2 = bias[2];
  const int parb = wv * 768;
#pragma unroll
  for (int ic4 = 0; ic4 < 16; ++ic4) {
    float4 xv[4];
#pragma unroll
    for (int t = 0; t < 4; ++t) {
      int lr = Ul + (t >> 1) + pr, lc = Vl + (t & 1) + pc;
      xv[t] = *(const float4*)&Xl[(lr * 18 + lc) * 68 + ic4 * 4];
    }
#pragma unroll
    for (int t = 0; t < 4; ++t) {
      float4 w0 = *(const float4*)&wl[parb + (t * 3 + 0) * 64 + ic4 * 4];
      float4 w1 = *(const float4*)&wl[parb + (t * 3 + 1) * 64 + ic4 * 4];
      float4 w2 = *(const float4*)&wl[parb + (t * 3 + 2) * 64 + ic4 * 4];
      a0 = fmaf(w0.x, xv[t].x, fmaf(w0.y, xv[t].y, fmaf(w0.z, xv[t].z, fmaf(w0.w, xv[t].w, a0))));
      a1 = fmaf(w1.x, xv[t].x, fmaf(w1.y, xv[t].y, fmaf(w1.z, xv[t].z, fmaf(w1.w, xv[t].w, a1))));
      a2 = fmaf(w2.x, xv[t].x, fmaf(w2.y, xv[t].y, fmaf(w2.z, xv[t].z, fmaf(w2.w, xv[t].w, a2))));
    }
  }
  const int r = r0 + 2 * Ul + pr, c = c0 + 2 * Vl + pc;
  float* yn = y + (size_t)n * 3 * 65536 + r * 256 + c;
  yn[0] = a0;
  yn[65536] = a1;
  yn[131072] = a2;
}

// ---------------------------------------------------------------------------
extern "C" void kernel_launch(void* const* d_in, const int* in_sizes, int n_in,
                              void* d_out, int out_size, void* d_ws, size_t ws_size,
                              hipStream_t stream)
{
  const float* x   = (const float*)d_in[0];
  const float* ew1 = (const float*)d_in[1];
  const float* eb1 = (const float*)d_in[2];
  const float* ew2 = (const float*)d_in[3];
  const float* eb2 = (const float*)d_in[4];
  const float* ew3 = (const float*)d_in[5];
  const float* eb3 = (const float*)d_in[6];
  const float* cb  = (const float*)d_in[7];
  const float* dw1 = (const float*)d_in[8];
  const float* db1 = (const float*)d_in[9];
  const float* dw2 = (const float*)d_in[10];
  const float* db2 = (const float*)d_in[11];
  const float* dw3 = (const float*)d_in[12];
  const float* db3 = (const float*)d_in[13];

  float* recon = (float*)d_out;
  float* idxf  = (float*)d_out + 3145728;

  const size_t MB = 1048576ull;
  char* ws = (char*)d_ws;
  // Workspace map (96 MiB, liveness-aliased):
  short* h1h = (short*)ws;                 // [0,32M)   conv1 out hi (fp16, x64)
  short* h1l = (short*)(ws + 32 * MB);     // [32M,64M) conv1 out lo
  short* h2h = (short*)(ws + 64 * MB);     // [64M,80M) conv2 out hi
  short* h2l = (short*)(ws + 80 * MB);     // [80M,96M) conv2 out lo
  // after conv2 (h1 dead):
  short* ft16  = (short*)ws;               // [0,8M)    conv3 out fp16 (single)
  float* featf = (float*)(ws + 16 * MB);   // [16M,32M) conv3 out fp32
  // after conv3 (h2 dead):
  short* cbh  = (short*)(ws + 64 * MB);    // [64M,68M)
  short* cbl  = (short*)(ws + 68 * MB);    // [68M,72M)
  short* cb16 = (short*)(ws + 72 * MB);    // [72M,76M)
  float4* t4v = (float4*)(ws + 80 * MB);   // [80M,82M) per-split top-4 packed (8 splits)
  int*    fidx = (int*)(ws + 92 * MB);     // [92M,+64K)
  // after vq_rescore (t4v dead):
  short* A1h = (short*)(ws + 76 * MB);     // 1 MB
  short* A1l = (short*)(ws + 77 * MB);     // 1 MB
  short* A2h = (short*)(ws + 78 * MB);     // 256 KB
  short* A2l = (short*)(ws + 78 * MB + 262144);
  short* qTh = (short*)ws;                 // [0,8M)   (ft16 dead)
  short* qTl = (short*)(ws + 8 * MB);      // [8M,16M)
  short* d1h = (short*)(ws + 32 * MB);     // [32M,48M)
  short* d1l = (short*)(ws + 48 * MB);     // [48M,64M)
  __half* d2 = (__half*)ws;                // [0,32M)  (qT dead)
  // conv weight packs live in d_out's recon region (overwritten by deconv3)
  short* W2h = (short*)recon;              // 128*1024 shorts
  short* W2l = W2h + 131072;
  short* W3h = W2h + 262144;               // 256*2048 shorts
  short* W3l = W2h + 786432;

  conv1_kernel<<<dim3(64, 16), 256, 0, stream>>>(x, ew1, eb1, h1h, h1l);
  wpack_conv<128, 64><<<dim3(512), 256, 0, stream>>>(ew2, W2h, W2l);
  conv_mfma<64, 128, 128, true, false><<<dim3(32, 1, 16), 256, 0, stream>>>(
      h1h, h1l, W2h, W2l, eb2, h2h, h2l, nullptr);
  wpack_conv<256, 128><<<dim3(2048), 256, 0, stream>>>(ew3, W3h, W3l);
  conv_mfma<128, 64, 256, false, true><<<dim3(8, 2, 16), 256, 0, stream>>>(
      h2h, h2l, W3h, W3l, eb3, ft16, nullptr, featf);

  cb_convert<<<dim3(1024), 256, 0, stream>>>(cb, cbh, cbl, cb16);
  vq_mfma<<<dim3(128, 8), 256, 0, stream>>>(cb16, ft16, t4v);
  vq_rescore<<<dim3(64), 256, 0, stream>>>(t4v, featf, cb, fidx, idxf);

  wpack<128, 256><<<dim3(2048), 256, 0, stream>>>(dw1, A1h, A1l);
  wpack<64, 128><<<dim3(512), 256, 0, stream>>>(dw2, A2h, A2l);
  gather2<<<dim3(256), 256, 0, stream>>>(cbh, cbl, fidx, qTh, qTl);

  deconv_mfma<256, 32, 128, 128, 2, 2, false>
      <<<dim3(8, 4, 16), 256, 0, stream>>>(qTh, qTl, A1h, A1l, db1, d1h, d1l);
  deconv_mfma<128, 64, 64, 256, 1, 4, true>
      <<<dim3(16, 4, 16), 256, 0, stream>>>(d1h, d1l, A2h, A2l, db2, d2, d2);
  deconv3_kernel<<<dim3(8, 32, 16), 256, 0, stream>>>(d2, dw3, db3, recon);
}

// Round 13
// 800.601 us; speedup vs baseline: 1.1114x; 1.1114x over previous
//
#include <hip/hip_runtime.h>
#include <hip/hip_fp16.h>
#include <cstdint>
#include <cstddef>

typedef __attribute__((ext_vector_type(8))) short short8;
typedef __attribute__((ext_vector_type(8))) _Float16 h16x8;
typedef __attribute__((ext_vector_type(4))) float f32x4;

// bf16 helpers (RNE)
__device__ __forceinline__ short f2bf(float x) {
  union { float f; unsigned u; } a; a.f = x;
  unsigned r = a.u + 0x7fff + ((a.u >> 16) & 1);
  return (short)(r >> 16);
}
__device__ __forceinline__ float bf2f(short s) {
  union { unsigned u; float f; } a;
  a.u = ((unsigned)(unsigned short)s) << 16; return a.f;
}
// fp16 hi/lo split (v is pre-scaled; residual captured in second fp16)
__device__ __forceinline__ void fsplit16(float v, short& h, short& l) {
  __half a = __float2half(v);
  h = (short)__half_as_ushort(a);
  l = (short)__half_as_ushort(__float2half(v - __half2float(a)));
}

// async global->LDS, 16B per lane; lds dest = wave-uniform base + lane*16
__device__ __forceinline__ void ld16(const void* g, void* l) {
  __builtin_amdgcn_global_load_lds(
      (const __attribute__((address_space(1))) unsigned int*)g,
      (__attribute__((address_space(3))) unsigned int*)l, 16, 0, 0);
}

// ---------------------------------------------------------------------------
// conv1: x[16,3,256,256] -> h1 channel-last fp16 hi/lo [16][128*128][64],
// values scaled x64. k=4 s=2 p=1, ReLU.
// ---------------------------------------------------------------------------
__global__ __launch_bounds__(256) void conv1_kernel(
    const float* __restrict__ x, const float* __restrict__ w,
    const float* __restrict__ bias, short* __restrict__ yh, short* __restrict__ yl)
{
  __shared__ __align__(16) float wl[64 * 48];
  __shared__ float bl[64];
  const int tid = threadIdx.x;
  for (int i = tid; i < 64 * 48; i += 256) wl[i] = w[i];
  if (tid < 64) bl[tid] = bias[tid];
  __syncthreads();
  const int n  = blockIdx.y;
  const int oh = blockIdx.x * 2 + (tid >> 7);
  const int ow = tid & 127;
  const float* xb = x + (size_t)n * 3 * 65536;
  const int ih0 = oh * 2 - 1, iw0 = ow * 2 - 1;
  float xin[48];
#pragma unroll
  for (int ic = 0; ic < 3; ++ic)
#pragma unroll
    for (int kh = 0; kh < 4; ++kh) {
      int ih = ih0 + kh;
      bool rok = (unsigned)ih < 256u;
#pragma unroll
      for (int kw = 0; kw < 4; ++kw) {
        int iw = iw0 + kw;
        xin[ic * 16 + kh * 4 + kw] =
            (rok && (unsigned)iw < 256u) ? xb[ic * 65536 + ih * 256 + iw] : 0.f;
      }
    }
  const size_t ob = ((size_t)n * 16384 + oh * 128 + ow) * 64;
  for (int g = 0; g < 8; ++g) {
    short hs[8], ls[8];
#pragma unroll
    for (int j = 0; j < 8; ++j) {
      const int oc = g * 8 + j;
      float acc = bl[oc];
      const float* wo = &wl[oc * 48];
#pragma unroll
      for (int t = 0; t < 48; ++t) acc = fmaf(wo[t], xin[t], acc);
      acc = fmaxf(acc, 0.f) * 64.f;
      fsplit16(acc, hs[j], ls[j]);
    }
    *(short8*)(yh + ob + g * 8) = *(short8*)hs;
    *(short8*)(yl + ob + g * 8) = *(short8*)ls;
  }
}

// ---------------------------------------------------------------------------
// wpack_conv: encoder conv weights OIHW fp32 -> Wp[oc][K] fp16 hi/lo, x64.
// ---------------------------------------------------------------------------
template <int COUT, int CIN>
__global__ __launch_bounds__(256) void wpack_conv(
    const float* __restrict__ w, short* __restrict__ Wh, short* __restrict__ Wl)
{
  constexpr int K = 16 * CIN;
  const int idx = blockIdx.x * 256 + threadIdx.x;
  const int oc = idx / K, k = idx - oc * K;
  const int kk = k / CIN, ic = k - kk * CIN;
  const int kh = kk >> 2, kw = kk & 3;
  float v = w[(((size_t)oc * CIN + ic) * 4 + kh) * 4 + kw] * 64.f;
  short h, l;
  fsplit16(v, h, l);
  Wh[idx] = h;
  Wl[idx] = l;
}

// ---------------------------------------------------------------------------
// conv_mfma v4: verified 2-buffer LDS structure (828us run), parameterized by
// MT (oc tile). MT=128: 4 waves 2x2 (wave 64oc x 64px). MT=64: 4 waves 1x4
// (wave 64oc x 32px) -> 2x the block count, 2x occupancy, for latency hiding
// of the HBM-resident B gather. Per-output accumulation order unchanged.
// ---------------------------------------------------------------------------
template <int CIN, int HIN, int COUTT, int MT, bool RELU, bool OUTF>
__global__ __launch_bounds__(256) void conv_mfma(
    const short* __restrict__ inh, const short* __restrict__ inl,
    const short* __restrict__ Wph, const short* __restrict__ Wpl,
    const float* __restrict__ bias,
    short* __restrict__ outh, short* __restrict__ outl,
    float* __restrict__ outf)
{
  constexpr int K = 16 * CIN;
  constexpr int HOUT = HIN / 2;
  constexpr int NPX = 128;
  constexpr int GS = (HOUT == 64) ? 6 : 5;
  constexpr int AE = 4 * MT;
  constexpr int NS = K / 32;  // even
  constexpr int WNW = (MT == 128) ? 2 : 4;   // waves along N
  constexpr int WPX = NPX / WNW;             // px per wave (64 or 32)
  constexpr int NTC = WPX / 16;              // nt frags (4 or 2)
  constexpr float RS = 1.f / 4096.f;
  __shared__ __align__(16) short AhL[2][AE * 8];
  __shared__ __align__(16) short AlL[2][AE * 8];
  __shared__ __align__(16) float bl[MT];
  const int tid = threadIdx.x;
  const int w = tid >> 6, lane = tid & 63;
  const int wm = (MT == 128) ? (w >> 1) : 0;
  const int wn = (MT == 128) ? (w & 1) : w;
  const int kgl = lane >> 4, cl = lane & 15;
  const int n = blockIdx.z;
  const int oc0 = blockIdx.y * MT;
  const int oh0 = blockIdx.x * (NPX / HOUT);
  if (tid < MT) bl[tid] = bias[oc0 + tid];

  f32x4 acc[4][NTC];
#pragma unroll
  for (int i = 0; i < 4; ++i)
#pragma unroll
    for (int j = 0; j < NTC; ++j) acc[i][j] = (f32x4){0.f, 0.f, 0.f, 0.f};

  auto stageA = [&](int s, int b) {
    const int kc = s * 32;
#pragma unroll
    for (int rep = 0; rep < AE / 256; ++rep) {
      int e = rep * 256 + tid;
      int kg = e / MT, oc_l = e % MT;
      size_t go = (size_t)(oc0 + oc_l) * K + kc + kg * 8;
      int lo = (e & ~63) * 8;
      ld16(Wph + go, &AhL[b][lo]);
      ld16(Wpl + go, &AlL[b][lo]);
    }
  };
  const h16x8 zzh = {0, 0, 0, 0, 0, 0, 0, 0};
  auto loadB = [&](int s, h16x8* bh, h16x8* blv) {
    const int kc = s * 32;
    const int kk = kc / CIN, ic0 = kc % CIN;
    const int kh = kk >> 2, kw = kk & 3;
#pragma unroll
    for (int nt = 0; nt < NTC; ++nt) {
      int m = wn * WPX + nt * 16 + cl;
      int ih = 2 * (oh0 + (m >> GS)) - 1 + kh;
      int iw = 2 * (m & (HOUT - 1)) - 1 + kw;
      bool ok = ((unsigned)ih < (unsigned)HIN) && ((unsigned)iw < (unsigned)HIN);
      size_t go = ok ? ((size_t)((n * HIN + ih) * HIN + iw) * CIN + ic0 + kgl * 8)
                     : (size_t)(ic0 + kgl * 8);
      h16x8 vh = *(const h16x8*)(inh + go);
      h16x8 vl = *(const h16x8*)(inl + go);
      bh[nt] = ok ? vh : zzh;
      blv[nt] = ok ? vl : zzh;
    }
  };
  auto compute = [&](int b, const h16x8* bh, const h16x8* blv) {
    h16x8 ah[4], al[4];
#pragma unroll
    for (int mt = 0; mt < 4; ++mt) {
      int row = kgl * MT + wm * 64 + mt * 16 + cl;
      ah[mt] = *(const h16x8*)&AhL[b][row * 8];
      al[mt] = *(const h16x8*)&AlL[b][row * 8];
    }
#pragma unroll
    for (int mt = 0; mt < 4; ++mt)
#pragma unroll
      for (int nt = 0; nt < NTC; ++nt) {
        acc[mt][nt] = __builtin_amdgcn_mfma_f32_16x16x32_f16(
            ah[mt], bh[nt], acc[mt][nt], 0, 0, 0);
        acc[mt][nt] = __builtin_amdgcn_mfma_f32_16x16x32_f16(
            ah[mt], blv[nt], acc[mt][nt], 0, 0, 0);
        acc[mt][nt] = __builtin_amdgcn_mfma_f32_16x16x32_f16(
            al[mt], bh[nt], acc[mt][nt], 0, 0, 0);
      }
  };

  h16x8 bhA[4], blA[4], bhB[4], blB[4];
  stageA(0, 0);
  loadB(0, bhA, blA);
  __syncthreads();
  for (int s2 = 0; s2 < NS; s2 += 2) {
    stageA(s2 + 1, 1);
    loadB(s2 + 1, bhB, blB);
    compute(0, bhA, blA);
    __syncthreads();
    if (s2 + 2 < NS) { stageA(s2 + 2, 0); loadB(s2 + 2, bhA, blA); }
    compute(1, bhB, blB);
    __syncthreads();
  }
  // C/D: oc = wm*64+mt*16+kgl*4+reg, px = wn*WPX+nt*16+cl
#pragma unroll
  for (int mt = 0; mt < 4; ++mt) {
    const int oc = wm * 64 + mt * 16 + kgl * 4;
    const float4 bv = *(const float4*)&bl[oc];
#pragma unroll
    for (int nt = 0; nt < NTC; ++nt) {
      const int px = wn * WPX + nt * 16 + cl;
      const int oh = oh0 + (px >> GS), ow = px & (HOUT - 1);
      const size_t ob =
          ((size_t)n * (HOUT * HOUT) + oh * HOUT + ow) * COUTT + oc0 + oc;
      float v0 = acc[mt][nt][0] * RS + bv.x;
      float v1 = acc[mt][nt][1] * RS + bv.y;
      float v2 = acc[mt][nt][2] * RS + bv.z;
      float v3 = acc[mt][nt][3] * RS + bv.w;
      if (RELU) {
        v0 = fmaxf(v0, 0.f); v1 = fmaxf(v1, 0.f);
        v2 = fmaxf(v2, 0.f); v3 = fmaxf(v3, 0.f);
      }
      if constexpr (OUTF) {
        ushort4 s;
        s.x = __half_as_ushort(__float2half(v0));
        s.y = __half_as_ushort(__float2half(v1));
        s.z = __half_as_ushort(__float2half(v2));
        s.w = __half_as_ushort(__float2half(v3));
        *(ushort4*)((unsigned short*)outh + ob) = s;
        *(float4*)(outf + ob) = make_float4(v0, v1, v2, v3);
      } else {
        short4 hh, ll;
        fsplit16(v0 * 64.f, hh.x, ll.x);
        fsplit16(v1 * 64.f, hh.y, ll.y);
        fsplit16(v2 * 64.f, hh.z, ll.z);
        fsplit16(v3 * 64.f, hh.w, ll.w);
        *(short4*)(outh + ob) = hh;
        *(short4*)(outl + ob) = ll;
      }
    }
  }
}

// ---------------------------------------------------------------------------
// cb_convert: codebook fp32 -> bf16 hi/lo (decoder gather) + fp16 (vq scoring)
// ---------------------------------------------------------------------------
__global__ __launch_bounds__(256) void cb_convert(
    const float* __restrict__ cb, short* __restrict__ cbh,
    short* __restrict__ cbl, short* __restrict__ cb16)
{
  const int g = blockIdx.x * 256 + threadIdx.x;
  const float* p = cb + (size_t)g * 8;
  short hs[8], ls[8], fs[8];
#pragma unroll
  for (int u = 0; u < 8; ++u) {
    float v = p[u];
    short h = f2bf(v);
    hs[u] = h;
    ls[u] = f2bf(v - bf2f(h));
    fs[u] = (short)__half_as_ushort(__float2half(v));
  }
  *(short8*)(cbh + (size_t)g * 8) = *(short8*)hs;
  *(short8*)(cbl + (size_t)g * 8) = *(short8*)ls;
  *(short8*)(cb16 + (size_t)g * 8) = *(short8*)fs;
}

// ---------------------------------------------------------------------------
// vq_mfma v10 (unchanged from the verified 828us run)
// ---------------------------------------------------------------------------
__global__ __launch_bounds__(256, 2) void vq_mfma(
    const short* __restrict__ cb16, const short* __restrict__ ft16,
    float4* __restrict__ t4v)
{
  __shared__ __align__(16) short Ah[3][4 * 128 * 8];  // 3 x 8 KB
  __shared__ __align__(16) float MrgV[256 * 4];       // 4 KB merge scratch
  const int tid = threadIdx.x;
  const int w = tid >> 6, lane = tid & 63;
  const int wm = w >> 1, wn = w & 1;
  const int tok0 = blockIdx.x * 128;
  const int split = blockIdx.y;  // 0..7, 1024 codes each
  const int kgl = lane >> 4, cl = lane & 15;
  const int i0 = w * 128;

  // B fragments: loaded once, live whole kernel (128 VGPR, all-static idx)
  h16x8 breg[8][4];
#pragma unroll
  for (int s = 0; s < 8; ++s)
#pragma unroll
    for (int nt = 0; nt < 4; ++nt)
      breg[s][nt] = *(const h16x8*)(ft16 +
          ((size_t)(tok0 + wn * 64 + nt * 16 + cl)) * 256 + s * 32 + kgl * 8);

  // stage A chunk g (tile = g>>3, s = g&7) into buffer b: 2 ld16 per thread
  auto stageA = [&](int g, int b) {
    const int tile = g >> 3, s = g & 7;
    const int code0 = split * 1024 + tile * 128;
    const int kc = s * 32;
#pragma unroll
    for (int rep = 0; rep < 2; ++rep) {
      int ib = i0 + rep * 64;
      int i = ib + lane;
      int m = i & 127, kg = i >> 7;
      size_t go = (size_t)(code0 + m) * 256 + kc + kg * 8;
      ld16(cb16 + go, &Ah[b][ib * 8]);
    }
  };

  f32x4 acc[4][4];

  // running top-2 per token column (index packed in low 11 mantissa bits)
  float m1[4], m2[4];
#pragma unroll
  for (int nt = 0; nt < 4; ++nt) { m1[nt] = -3.4e38f; m2[nt] = -3.4e38f; }
  const unsigned orbase0 = (unsigned)(wm * 64 + kgl * 4);
  auto fold = [&](int tile) {
    const unsigned orb = (unsigned)(tile * 128) + orbase0;
#pragma unroll
    for (int nt = 0; nt < 4; ++nt)
#pragma unroll
      for (int mt = 0; mt < 4; ++mt)
#pragma unroll
        for (int r = 0; r < 4; ++r) {
          union { float f; unsigned u; } pv;
          pv.f = acc[mt][nt][r];
          pv.u = (pv.u & 0xFFFFF800u) | (orb + (unsigned)(mt * 16 + r));
          float t = fminf(m1[nt], pv.f);
          m1[nt] = fmaxf(m1[nt], pv.f);
          m2[nt] = fmaxf(m2[nt], t);
        }
  };

  // one chunk's compute: STATIC s (breg index), runtime LDS buffer b
  auto computeS = [&](int b, int s_static, bool first) {
    h16x8 ah[4];
#pragma unroll
    for (int mt = 0; mt < 4; ++mt) {
      int row = wm * 64 + mt * 16 + cl;
      ah[mt] = *(const h16x8*)&Ah[b][(kgl * 128 + row) * 8];
    }
    if (first) {
      f32x4 z4 = (f32x4){0.f, 0.f, 0.f, 0.f};
#pragma unroll
      for (int mt = 0; mt < 4; ++mt)
#pragma unroll
        for (int nt = 0; nt < 4; ++nt)
          acc[mt][nt] = __builtin_amdgcn_mfma_f32_16x16x32_f16(
              ah[mt], breg[s_static][nt], z4, 0, 0, 0);
    } else {
#pragma unroll
      for (int mt = 0; mt < 4; ++mt)
#pragma unroll
        for (int nt = 0; nt < 4; ++nt)
          acc[mt][nt] = __builtin_amdgcn_mfma_f32_16x16x32_f16(
              ah[mt], breg[s_static][nt], acc[mt][nt], 0, 0, 0);
    }
  };

  // pipeline: depth-2 prefetch, counted vmcnt, raw barriers.
  stageA(0, 0);
  stageA(1, 1);
  asm volatile("s_waitcnt vmcnt(0)" ::: "memory");
  __builtin_amdgcn_sched_barrier(0);
  __builtin_amdgcn_s_barrier();
  for (int tile = 0; tile < 7; ++tile) {
#pragma unroll
    for (int s = 0; s < 8; ++s) {   // s is compile-time under full unroll
      const int g = tile * 8 + s;
      asm volatile("s_waitcnt vmcnt(2)" ::: "memory");
      __builtin_amdgcn_sched_barrier(0);
      __builtin_amdgcn_s_barrier();
      computeS(g % 3, s, s == 0);
      stageA(g + 2, (g + 2) % 3);   // max g+2 = 57 < 64
    }
    fold(tile);
  }
#pragma unroll
  for (int s = 0; s < 8; ++s) {     // tile 7: g = 56..63
    const int g = 56 + s;
    if (s < 7) {
      asm volatile("s_waitcnt vmcnt(2)" ::: "memory");
    } else {
      asm volatile("s_waitcnt vmcnt(0)" ::: "memory");
    }
    __builtin_amdgcn_sched_barrier(0);
    __builtin_amdgcn_s_barrier();
    computeS(g % 3, s, s == 0);
    if (g + 2 < 64) stageA(g + 2, (g + 2) % 3);
  }
  fold(7);

  // merge: butterfly over kgl (lanes ^16, ^32), then cross-wm via LDS
#pragma unroll
  for (int nt = 0; nt < 4; ++nt) {
    float mv[4] = {m1[nt], m2[nt], -3.4e38f, -3.4e38f};
#pragma unroll
    for (int st = 16; st < 64; st <<= 1) {
      float ov[4];
#pragma unroll
      for (int k = 0; k < 4; ++k) ov[k] = __shfl_xor(mv[k], st);
#pragma unroll
      for (int k = 0; k < 4; ++k) {
        if (ov[k] > mv[3]) {
          mv[3] = ov[k];
#pragma unroll
          for (int q = 3; q > 0; --q)
            if (mv[q] > mv[q - 1]) {
              float tv = mv[q]; mv[q] = mv[q - 1]; mv[q - 1] = tv;
            }
        }
      }
    }
    if (lane < 16) {
      int tl = wn * 64 + nt * 16 + cl;
#pragma unroll
      for (int k = 0; k < 4; ++k) MrgV[(wm * 128 + tl) * 4 + k] = mv[k];
    }
  }
  __syncthreads();
  if (tid < 128) {
    int tl = tid;
    float mv[4];
#pragma unroll
    for (int k = 0; k < 4; ++k) mv[k] = MrgV[tl * 4 + k];
#pragma unroll
    for (int k = 0; k < 4; ++k) {
      float ov = MrgV[(128 + tl) * 4 + k];
      if (ov > mv[3]) {
        mv[3] = ov;
#pragma unroll
        for (int q = 3; q > 0; --q)
          if (mv[q] > mv[q - 1]) {
            float tv = mv[q]; mv[q] = mv[q - 1]; mv[q - 1] = tv;
          }
      }
    }
    size_t o = (size_t)split * 16384 + tok0 + tl;
    t4v[o] = make_float4(mv[0], mv[1], mv[2], mv[3]);
  }
}

// ---------------------------------------------------------------------------
// vq_rescore: 8 splits x top-4 packed candidates (id in low mantissa bits) ->
// keep top-4 by packed fp16-score, exact fp32 rescore vs featc, argmax
// (idx-asc tie-break).
// ---------------------------------------------------------------------------
__global__ __launch_bounds__(256) void vq_rescore(
    const float4* __restrict__ t4v, const float* __restrict__ featc,
    const float* __restrict__ cb, int* __restrict__ fidx,
    float* __restrict__ idx_out)
{
  const int t = blockIdx.x * 256 + threadIdx.x;
  float vs[4] = {-3.4e38f, -3.4e38f, -3.4e38f, -3.4e38f};
  int is[4] = {0, 0, 0, 0};
#pragma unroll
  for (int sp = 0; sp < 8; ++sp) {
    float4 v4 = t4v[(size_t)sp * 16384 + t];
    float vv[4] = {v4.x, v4.y, v4.z, v4.w};
#pragma unroll
    for (int k = 0; k < 4; ++k) {
      float v = vv[k];
      union { float f; unsigned u; } pu; pu.f = v;
      int ii = sp * 1024 + (int)(pu.u & 0x7FFu);
      if (v > vs[3]) {
        vs[3] = v; is[3] = ii;
#pragma unroll
        for (int q = 3; q > 0; --q)
          if (vs[q] > vs[q - 1]) {
            float tv = vs[q]; vs[q] = vs[q - 1]; vs[q - 1] = tv;
            int ti = is[q]; is[q] = is[q - 1]; is[q - 1] = ti;
          }
      }
    }
  }
  const float4* fc = (const float4*)(featc + (size_t)t * 256);
  const float4* c0 = (const float4*)(cb + (size_t)is[0] * 256);
  const float4* c1 = (const float4*)(cb + (size_t)is[1] * 256);
  const float4* c2 = (const float4*)(cb + (size_t)is[2] * 256);
  const float4* c3 = (const float4*)(cb + (size_t)is[3] * 256);
  float s0 = 0.f, s1 = 0.f, s2 = 0.f, s3 = 0.f;
  for (int k4 = 0; k4 < 64; ++k4) {
    float4 f = fc[k4];
    float4 w0 = c0[k4], w1 = c1[k4], w2 = c2[k4], w3 = c3[k4];
    s0 = fmaf(w0.x, f.x, fmaf(w0.y, f.y, fmaf(w0.z, f.z, fmaf(w0.w, f.w, s0))));
    s1 = fmaf(w1.x, f.x, fmaf(w1.y, f.y, fmaf(w1.z, f.z, fmaf(w1.w, f.w, s1))));
    s2 = fmaf(w2.x, f.x, fmaf(w2.y, f.y, fmaf(w2.z, f.z, fmaf(w2.w, f.w, s2))));
    s3 = fmaf(w3.x, f.x, fmaf(w3.y, f.y, fmaf(w3.z, f.z, fmaf(w3.w, f.w, s3))));
  }
  float best = s0; int bi = is[0];
  float sv[3] = {s1, s2, s3};
  int si2[3] = {is[1], is[2], is[3]};
#pragma unroll
  for (int c = 0; c < 3; ++c)
    if (sv[c] > best || (sv[c] == best && si2[c] < bi)) { best = sv[c]; bi = si2[c]; }
  fidx[t] = bi;
  idx_out[t] = (float)bi;
}

// ---------------------------------------------------------------------------
// wpack: deconv weights -> Apack[par][oc][K], K=(kk*CIN+ic), bf16 hi/lo.
// ---------------------------------------------------------------------------
template <int COUT, int CIN>
__global__ __launch_bounds__(256) void wpack(
    const float* __restrict__ w, short* __restrict__ Ah, short* __restrict__ Al)
{
  constexpr int K = 4 * CIN;
  const int idx = blockIdx.x * 256 + threadIdx.x;
  const int par = idx / (COUT * K);
  const int rem = idx % (COUT * K);
  const int oc = rem / K;
  const int k = rem % K;
  const int kk = k / CIN, ic = k % CIN;
  const int kh = 2 * (kk >> 1) + (par >> 1);
  const int kw = 2 * (kk & 1) + (par & 1);
  float v = w[(((size_t)oc * CIN + ic) * 4 + kh) * 4 + kw];
  short h = f2bf(v);
  Ah[idx] = h;
  Al[idx] = f2bf(v - bf2f(h));
}

// ---------------------------------------------------------------------------
// gather2: qT[token][ch] bf16 hi/lo = rows of cbh/cbl (pure row copy).
// ---------------------------------------------------------------------------
__global__ __launch_bounds__(256) void gather2(
    const short* __restrict__ cbh, const short* __restrict__ cbl,
    const int* __restrict__ fidx, short* __restrict__ qTh, short* __restrict__ qTl)
{
  const int tid = threadIdx.x;
  const int gt = blockIdx.x * 64 + (tid >> 2);
  const int part = tid & 3;
  const int code = fidx[gt];
  const short8* sh = (const short8*)(cbh + (size_t)code * 256 + part * 64);
  const short8* sl = (const short8*)(cbl + (size_t)code * 256 + part * 64);
  short8* dh = (short8*)(qTh + (size_t)gt * 256 + part * 64);
  short8* dl = (short8*)(qTl + (size_t)gt * 256 + part * 64);
#pragma unroll
  for (int j = 0; j < 8; ++j) { dh[j] = sh[j]; dl[j] = sl[j]; }
}

// ---------------------------------------------------------------------------
// deconv_mfma: ConvTranspose2d(k4,s2,p1)+ReLU as per-parity GEMM, bf16x3 MFMA.
// (unchanged from the verified 828us run)
// ---------------------------------------------------------------------------
template <int CIN, int GRID, int COUT, int NPX, int WM, int WN, bool OUT_HALF>
__global__ __launch_bounds__(256) void deconv_mfma(
    const short* __restrict__ inh, const short* __restrict__ inl,
    const short* __restrict__ Aph, const short* __restrict__ Apl,
    const float* __restrict__ bias, void* __restrict__ out_h,
    void* __restrict__ out_l)
{
  constexpr int K = 4 * CIN, HOUT = 2 * GRID, AE = 4 * COUT;
  constexpr int GS = (GRID == 32) ? 5 : 6;
  constexpr int NS = K / 32;  // even
  __shared__ __align__(16) short AhL[2][AE * 8];
  __shared__ __align__(16) short AlL[2][AE * 8];
  __shared__ float bl[COUT];
  const int tid = threadIdx.x;
  const int w = tid >> 6, lane = tid & 63;
  const int wm = w / WN, wn = w % WN;
  const int kgl = lane >> 4, cl = lane & 15;
  const int par = blockIdx.y, n = blockIdx.z;
  const int pr = par >> 1, pc = par & 1;
  const int Ut0 = blockIdx.x * (NPX / GRID);
  if (tid < COUT) bl[tid] = bias[tid];

  f32x4 acc[4][4];
#pragma unroll
  for (int i = 0; i < 4; ++i)
#pragma unroll
    for (int j = 0; j < 4; ++j) acc[i][j] = (f32x4){0.f, 0.f, 0.f, 0.f};

  auto stageA = [&](int s, int b) {
    const int kc = s * 32;
#pragma unroll
    for (int rep = 0; rep < AE / 256; ++rep) {
      int e = rep * 256 + tid;
      int kg = e / COUT, oc_l = e % COUT;
      size_t go = ((size_t)(par * COUT + oc_l)) * K + kc + kg * 8;
      int lo = (e & ~63) * 8;
      ld16(Aph + go, &AhL[b][lo]);
      ld16(Apl + go, &AlL[b][lo]);
    }
  };
  const short8 zz = {0, 0, 0, 0, 0, 0, 0, 0};
  auto loadB = [&](int s, short8* bh, short8* blo) {
    const int kc = s * 32;
    const int kk = kc / CIN, ic0 = kc % CIN;
    const int dr = (kk >> 1) + pr - 1, dc = (kk & 1) + pc - 1;
#pragma unroll
    for (int nt = 0; nt < 4; ++nt) {
      int m = wn * 64 + nt * 16 + cl;
      int sU = Ut0 + (m >> GS) + dr;
      int sV = (m & (GRID - 1)) + dc;
      bool ok = (unsigned)sU < (unsigned)GRID && (unsigned)sV < (unsigned)GRID;
      long pix = (long)(n * GRID + sU) * GRID + sV;
      size_t go = ok ? (size_t)(pix * CIN + ic0 + kgl * 8)
                     : (size_t)(ic0 + kgl * 8);
      short8 vh = *(const short8*)(inh + go);
      short8 vl = *(const short8*)(inl + go);
      bh[nt] = ok ? vh : zz;
      blo[nt] = ok ? vl : zz;
    }
  };
  auto compute = [&](int b, const short8* bh, const short8* blo) {
    short8 ah[4], al[4];
#pragma unroll
    for (int mt = 0; mt < 4; ++mt) {
      int row = kgl * COUT + wm * 64 + mt * 16 + cl;
      ah[mt] = *(const short8*)&AhL[b][row * 8];
      al[mt] = *(const short8*)&AlL[b][row * 8];
    }
#pragma unroll
    for (int mt = 0; mt < 4; ++mt)
#pragma unroll
      for (int nt = 0; nt < 4; ++nt) {
        acc[mt][nt] = __builtin_amdgcn_mfma_f32_16x16x32_bf16(
            ah[mt], bh[nt], acc[mt][nt], 0, 0, 0);
        acc[mt][nt] = __builtin_amdgcn_mfma_f32_16x16x32_bf16(
            ah[mt], blo[nt], acc[mt][nt], 0, 0, 0);
        acc[mt][nt] = __builtin_amdgcn_mfma_f32_16x16x32_bf16(
            al[mt], bh[nt], acc[mt][nt], 0, 0, 0);
      }
  };

  short8 bhA[4], blA[4], bhB[4], blB[4];
  stageA(0, 0);
  loadB(0, bhA, blA);
  __syncthreads();
  for (int s2 = 0; s2 < NS; s2 += 2) {
    stageA(s2 + 1, 1);
    loadB(s2 + 1, bhB, blB);
    compute(0, bhA, blA);
    __syncthreads();
    if (s2 + 2 < NS) { stageA(s2 + 2, 0); loadB(s2 + 2, bhA, blA); }
    compute(1, bhB, blB);
    __syncthreads();
  }
#pragma unroll
  for (int mt = 0; mt < 4; ++mt) {
    const int oc = wm * 64 + mt * 16 + kgl * 4;
    const float4 bv = *(const float4*)&bl[oc];
#pragma unroll
    for (int nt = 0; nt < 4; ++nt) {
      const int px = wn * 64 + nt * 16 + cl;
      const int U = Ut0 + (px >> GS), V = px & (GRID - 1);
      const int r = 2 * U + pr, c = 2 * V + pc;
      const size_t ob = ((size_t)n * HOUT * HOUT + (size_t)r * HOUT + c) * COUT + oc;
      float v0 = fmaxf(acc[mt][nt][0] + bv.x, 0.f);
      float v1 = fmaxf(acc[mt][nt][1] + bv.y, 0.f);
      float v2 = fmaxf(acc[mt][nt][2] + bv.z, 0.f);
      float v3 = fmaxf(acc[mt][nt][3] + bv.w, 0.f);
      if constexpr (OUT_HALF) {
        ushort4 s;
        s.x = __half_as_ushort(__float2half(v0));
        s.y = __half_as_ushort(__float2half(v1));
        s.z = __half_as_ushort(__float2half(v2));
        s.w = __half_as_ushort(__float2half(v3));
        *(ushort4*)((unsigned short*)out_h + ob) = s;
      } else {
        short4 hh, ll;
        hh.x = f2bf(v0); ll.x = f2bf(v0 - bf2f(hh.x));
        hh.y = f2bf(v1); ll.y = f2bf(v1 - bf2f(hh.y));
        hh.z = f2bf(v2); ll.z = f2bf(v2 - bf2f(hh.z));
        hh.w = f2bf(v3); ll.w = f2bf(v3 - bf2f(hh.w));
        *(short4*)((short*)out_h + ob) = hh;
        *(short4*)((short*)out_l + ob) = ll;
      }
    }
  }
}

// ---------------------------------------------------------------------------
// deconv3: d2T[n][pix(128x128)][64] fp16 -> recon[16,3,256,256] (no ReLU).
// ---------------------------------------------------------------------------
__global__ __launch_bounds__(256) void deconv3_kernel(
    const __half* __restrict__ d2, const float* __restrict__ w,
    const float* __restrict__ bias, float* __restrict__ y)
{
  __shared__ __align__(16) float Xl[108 * 68];
  __shared__ __align__(16) float wl[4 * 4 * 3 * 64];
  const int tid = threadIdx.x;
  for (int i = tid; i < 3072; i += 256) {
    int oc = i >> 10, ic = (i >> 4) & 63, kh = (i >> 2) & 3, kw = i & 3;
    int par = (kh & 1) * 2 + (kw & 1), kidx = (kh >> 1) * 2 + (kw >> 1);
    wl[((par * 4 + kidx) * 3 + oc) * 64 + ic] = w[i];
  }
  const int n = blockIdx.z, r0 = blockIdx.y * 8, c0 = blockIdx.x * 32;
  const int gr0 = (r0 >> 1) - 1, gc0 = (c0 >> 1) - 1;
  for (int e = tid; e < 1728; e += 256) {
    int pl = e >> 4, sub = e & 15;
    int rr = pl / 18, cc = pl - rr * 18;
    int gr = gr0 + rr, gc = gc0 + cc;
    float4 v = make_float4(0.f, 0.f, 0.f, 0.f);
    if ((unsigned)gr < 128u && (unsigned)gc < 128u) {
      const __half2* p =
          (const __half2*)(d2 + ((size_t)(n * 16384 + gr * 128 + gc) * 64 + sub * 4));
      float2 f0 = __half22float2(p[0]);
      float2 f1 = __half22float2(p[1]);
      v = make_float4(f0.x, f0.y, f1.x, f1.y);
    }
    *(float4*)&Xl[pl * 68 + sub * 4] = v;
  }
  __syncthreads();
  const int wv = tid >> 6, lane = tid & 63;
  const int pr = wv >> 1, pc = wv & 1;
  const int Ul = lane >> 4, Vl = lane & 15;
  float a0 = bias[0], a1 = bias[1], a2 = bias[2];
  const int parb = wv * 768;
#pragma unroll
  for (int ic4 = 0; ic4 < 16; ++ic4) {
    float4 xv[4];
#pragma unroll
    for (int t = 0; t < 4; ++t) {
      int lr = Ul + (t >> 1) + pr, lc = Vl + (t & 1) + pc;
      xv[t] = *(const float4*)&Xl[(lr * 18 + lc) * 68 + ic4 * 4];
    }
#pragma unroll
    for (int t = 0; t < 4; ++t) {
      float4 w0 = *(const float4*)&wl[parb + (t * 3 + 0) * 64 + ic4 * 4];
      float4 w1 = *(const float4*)&wl[parb + (t * 3 + 1) * 64 + ic4 * 4];
      float4 w2 = *(const float4*)&wl[parb + (t * 3 + 2) * 64 + ic4 * 4];
      a0 = fmaf(w0.x, xv[t].x, fmaf(w0.y, xv[t].y, fmaf(w0.z, xv[t].z, fmaf(w0.w, xv[t].w, a0))));
      a1 = fmaf(w1.x, xv[t].x, fmaf(w1.y, xv[t].y, fmaf(w1.z, xv[t].z, fmaf(w1.w, xv[t].w, a1))));
      a2 = fmaf(w2.x, xv[t].x, fmaf(w2.y, xv[t].y, fmaf(w2.z, xv[t].z, fmaf(w2.w, xv[t].w, a2))));
    }
  }
  const int r = r0 + 2 * Ul + pr, c = c0 + 2 * Vl + pc;
  float* yn = y + (size_t)n * 3 * 65536 + r * 256 + c;
  yn[0] = a0;
  yn[65536] = a1;
  yn[131072] = a2;
}

// ---------------------------------------------------------------------------
extern "C" void kernel_launch(void* const* d_in, const int* in_sizes, int n_in,
                              void* d_out, int out_size, void* d_ws, size_t ws_size,
                              hipStream_t stream)
{
  const float* x   = (const float*)d_in[0];
  const float* ew1 = (const float*)d_in[1];
  const float* eb1 = (const float*)d_in[2];
  const float* ew2 = (const float*)d_in[3];
  const float* eb2 = (const float*)d_in[4];
  const float* ew3 = (const float*)d_in[5];
  const float* eb3 = (const float*)d_in[6];
  const float* cb  = (const float*)d_in[7];
  const float* dw1 = (const float*)d_in[8];
  const float* db1 = (const float*)d_in[9];
  const float* dw2 = (const float*)d_in[10];
  const float* db2 = (const float*)d_in[11];
  const float* dw3 = (const float*)d_in[12];
  const float* db3 = (const float*)d_in[13];

  float* recon = (float*)d_out;
  float* idxf  = (float*)d_out + 3145728;

  const size_t MB = 1048576ull;
  char* ws = (char*)d_ws;
  // Workspace map (96 MiB, liveness-aliased):
  short* h1h = (short*)ws;                 // [0,32M)   conv1 out hi (fp16, x64)
  short* h1l = (short*)(ws + 32 * MB);     // [32M,64M) conv1 out lo
  short* h2h = (short*)(ws + 64 * MB);     // [64M,80M) conv2 out hi
  short* h2l = (short*)(ws + 80 * MB);     // [80M,96M) conv2 out lo
  // after conv2 (h1 dead):
  short* ft16  = (short*)ws;               // [0,8M)    conv3 out fp16 (single)
  float* featf = (float*)(ws + 16 * MB);   // [16M,32M) conv3 out fp32
  // after conv3 (h2 dead):
  short* cbh  = (short*)(ws + 64 * MB);    // [64M,68M)
  short* cbl  = (short*)(ws + 68 * MB);    // [68M,72M)
  short* cb16 = (short*)(ws + 72 * MB);    // [72M,76M)
  float4* t4v = (float4*)(ws + 80 * MB);   // [80M,82M) per-split top-4 packed (8 splits)
  int*    fidx = (int*)(ws + 92 * MB);     // [92M,+64K)
  // after vq_rescore (t4v dead):
  short* A1h = (short*)(ws + 76 * MB);     // 1 MB
  short* A1l = (short*)(ws + 77 * MB);     // 1 MB
  short* A2h = (short*)(ws + 78 * MB);     // 256 KB
  short* A2l = (short*)(ws + 78 * MB + 262144);
  short* qTh = (short*)ws;                 // [0,8M)   (ft16 dead)
  short* qTl = (short*)(ws + 8 * MB);      // [8M,16M)
  short* d1h = (short*)(ws + 32 * MB);     // [32M,48M)
  short* d1l = (short*)(ws + 48 * MB);     // [48M,64M)
  __half* d2 = (__half*)ws;                // [0,32M)  (qT dead)
  // conv weight packs live in d_out's recon region (overwritten by deconv3)
  short* W2h = (short*)recon;              // 128*1024 shorts
  short* W2l = W2h + 131072;
  short* W3h = W2h + 262144;               // 256*2048 shorts
  short* W3l = W2h + 786432;

  conv1_kernel<<<dim3(64, 16), 256, 0, stream>>>(x, ew1, eb1, h1h, h1l);
  wpack_conv<128, 64><<<dim3(512), 256, 0, stream>>>(ew2, W2h, W2l);
  conv_mfma<64, 128, 128, 64, true, false><<<dim3(32, 2, 16), 256, 0, stream>>>(
      h1h, h1l, W2h, W2l, eb2, h2h, h2l, nullptr);
  wpack_conv<256, 128><<<dim3(2048), 256, 0, stream>>>(ew3, W3h, W3l);
  conv_mfma<128, 64, 256, 64, false, true><<<dim3(8, 4, 16), 256, 0, stream>>>(
      h2h, h2l, W3h, W3l, eb3, ft16, nullptr, featf);

  cb_convert<<<dim3(1024), 256, 0, stream>>>(cb, cbh, cbl, cb16);
  vq_mfma<<<dim3(128, 8), 256, 0, stream>>>(cb16, ft16, t4v);
  vq_rescore<<<dim3(64), 256, 0, stream>>>(t4v, featf, cb, fidx, idxf);

  wpack<128, 256><<<dim3(2048), 256, 0, stream>>>(dw1, A1h, A1l);
  wpack<64, 128><<<dim3(512), 256, 0, stream>>>(dw2, A2h, A2l);
  gather2<<<dim3(256), 256, 0, stream>>>(cbh, cbl, fidx, qTh, qTl);

  deconv_mfma<256, 32, 128, 128, 2, 2, false>
      <<<dim3(8, 4, 16), 256, 0, stream>>>(qTh, qTl, A1h, A1l, db1, d1h, d1l);
  deconv_mfma<128, 64, 64, 256, 1, 4, true>
      <<<dim3(16, 4, 16), 256, 0, stream>>>(d1h, d1l, A2h, A2l, db2, d2, d2);
  deconv3_kernel<<<dim3(8, 32, 16), 256, 0, stream>>>(d2, dw3, db3, recon);
}